// Round 6
// baseline (298.616 us; speedup 1.0000x reference)
//
#include <hip/hip_runtime.h>

// Problem constants
#define Bc 2
#define Sc 1024
#define Dc 1024
#define Hc 2048
#define Ec 8
#define Kc 2
#define Tc (Bc*Sc)      // 2048 tokens
#define Pc (Tc*Kc)      // 4096 jobs
#define PADROWS 128     // tile-overrun padding for Xg / hidden (row-clamped staging)
#define MAXTILES 40     // 128-row tiles: sum_e ceil(cnt_e/128) <= 40 (40%8==0 -> XCD grouping)
#define MAXT256 24      // 256-row tiles: sum_e ceil(cnt_e/256) <= 24 (24%8==0)

typedef __bf16 bf16x8 __attribute__((ext_vector_type(8)));
typedef float floatx4 __attribute__((ext_vector_type(4)));
typedef unsigned short ushort4_t __attribute__((ext_vector_type(4)));
typedef unsigned short ushort8_t __attribute__((ext_vector_type(8)));

__device__ inline unsigned short f2bf(float f) {
    unsigned u = __builtin_bit_cast(unsigned, f);
    unsigned r = u + 0x7fffu + ((u >> 16) & 1u);   // RNE
    return (unsigned short)(r >> 16);
}

// flax nn.gelu approximate=True: 0.5v(1+tanh(y)) == v * sigmoid(2y)
__device__ inline float gelu_fast(float v) {
    float z = 1.5957691216057308f * (v + 0.044715f * v * v * v);  // 2y
    return v / (1.0f + __expf(-z));
}

// async global->LDS, 16B per lane; LDS dest = wave-uniform base + lane*16
__device__ inline void gload_lds16(const void* g, void* l) {
    __builtin_amdgcn_global_load_lds((const __attribute__((address_space(1))) unsigned int*)g,
                                     (__attribute__((address_space(3))) unsigned int*)l,
                                     16, 0, 0);
}

// ---------- LDS staging helpers ----------
// Tile rows are 64 bf16 = 128B = 8 chunks of 16B. Physical chunk = logical ^ (ldsrow & 7)
// (XOR swizzle; R4 measured: SQ_LDS_BANK_CONFLICT -> 0). Lane i covers ldsrow i>>3,
// physical chunk i&7 -> fetches logical chunk (i&7)^(ldsrow&7). Global row clamped to
// rowmax (overrun rows carry garbage, masked in epilogue).
__device__ inline void stage32(const unsigned short* __restrict__ mat, int ld, int row0,
                               int rowmax, int kk, char* ldsdst, int lane) {
    int rr = lane >> 3, cp = lane & 7;
#pragma unroll
    for (int j = 0; j < 4; j++) {
        int lrow = j * 8 + rr;
        int row = row0 + lrow;
        row = row < rowmax ? row : rowmax;
        int cl = cp ^ (lrow & 7);
        const unsigned short* g = mat + (size_t)row * ld + kk + cl * 8;
        gload_lds16(g, ldsdst + (size_t)(j * 8) * 128);
    }
}

__device__ inline void stage16(const unsigned short* __restrict__ mat, int ld, int row0,
                               int kk, char* ldsdst, int lane) {
    int rr = lane >> 3, cp = lane & 7;
#pragma unroll
    for (int j = 0; j < 2; j++) {
        int lrow = j * 8 + rr;
        int cl = cp ^ (lrow & 7);
        const unsigned short* g = mat + (size_t)(row0 + lrow) * ld + kk + cl * 8;
        gload_lds16(g, ldsdst + (size_t)(j * 8) * 128);
    }
}

// ---------- single-block bucketing: counts + prefix + tile lists + job fill ----------
__global__ void bucket_kernel(const int* __restrict__ idx, const float* __restrict__ wts,
                              int* __restrict__ counts, int* __restrict__ offs,
                              int* __restrict__ tile_e, int* __restrict__ tile_m0,
                              int* __restrict__ t256_e, int* __restrict__ t256_m0,
                              int* __restrict__ n_tiles, int* __restrict__ n_t256,
                              int* __restrict__ job_token, float* __restrict__ job_w) {
    __shared__ int lc[Ec], lf[Ec], lo[Ec];
    int t = threadIdx.x;
    if (t < Ec) { lc[t] = 0; lf[t] = 0; }
    __syncthreads();
    int myid[Pc / 256];
#pragma unroll
    for (int j = 0; j < Pc / 256; j++) {
        int i = t + j * 256;
        myid[j] = idx[i];
        atomicAdd(&lc[myid[j]], 1);
    }
    __syncthreads();
    if (t == 0) {
        int s = 0, tt = 0, t2 = 0;
        for (int e = 0; e < Ec; e++) {
            lo[e] = s; offs[e] = s; counts[e] = lc[e];
            for (int m0 = 0; m0 < lc[e]; m0 += 128) { tile_e[tt] = e; tile_m0[tt] = m0; tt++; }
            for (int m0 = 0; m0 < lc[e]; m0 += 256) { t256_e[t2] = e; t256_m0[t2] = m0; t2++; }
            s += lc[e];
        }
        offs[Ec] = s;
        *n_tiles = tt;
        *n_t256 = t2;
    }
    __syncthreads();
#pragma unroll
    for (int j = 0; j < Pc / 256; j++) {
        int i = t + j * 256;
        int e = myid[j];
        int pos = lo[e] + atomicAdd(&lf[e], 1);
        job_token[pos] = i >> 1;          // i = token*K + k
        job_w[pos] = wts[i];
    }
}

// ---------- fp32 -> bf16 conversion of BOTH weight tensors in one launch ----------
__global__ void convert2_kernel(const float* __restrict__ a, unsigned short* __restrict__ da,
                                const float* __restrict__ b, unsigned short* __restrict__ db,
                                int n8each) {
    int i = blockIdx.x * 256 + threadIdx.x;
    const float* s; unsigned short* d; int j;
    if (i < n8each) { s = a; d = da; j = i; }
    else            { s = b; d = db; j = i - n8each; if (j >= n8each) return; }
    float4 v0 = ((const float4*)s)[2 * j];
    float4 v1 = ((const float4*)s)[2 * j + 1];
    ushort8_t o = { f2bf(v0.x), f2bf(v0.y), f2bf(v0.z), f2bf(v0.w),
                    f2bf(v1.x), f2bf(v1.y), f2bf(v1.z), f2bf(v1.w) };
    ((ushort8_t*)d)[j] = o;
}

// ---------- gather selected x rows into compact bf16 matrix ----------
__global__ void gather_kernel(const float* __restrict__ x, const int* __restrict__ job_token,
                              unsigned short* __restrict__ Xg) {
    int row = blockIdx.x;                  // 0..Pc-1
    int tok = job_token[row];
    int j = threadIdx.x;                   // 256 threads x 4 elems = 1024
    float4 v = ((const float4*)(x + (size_t)tok * Dc))[j];
    ushort4_t o = { f2bf(v.x), f2bf(v.y), f2bf(v.z), f2bf(v.w) };
    *(ushort4_t*)(Xg + (size_t)row * Dc + j * 4) = o;
}

#define BK 64

// ================== GEMM1: hidden = gelu(Xg . keys^T) ==================
// 128x128 tile, 4 waves, single-buffered (R4-proven). Grid: x = m-tile (fastest,
// 40%8==0 -> same-m blocks share an XCD's L2 for the A-tile), y = n-tile.
__global__ __launch_bounds__(256, 2) void gemm1_kernel(
    const unsigned short* __restrict__ Xg,      // [Pc+PADROWS, 1024] bf16
    const unsigned short* __restrict__ keysb,   // [E, 2048, 1024] bf16
    const int* __restrict__ counts, const int* __restrict__ offs,
    const int* __restrict__ tile_e, const int* __restrict__ tile_m0,
    const int* __restrict__ n_tiles,
    unsigned short* __restrict__ hidden)        // [Pc+PADROWS, 2048] bf16
{
    int ty = blockIdx.x;
    if (ty >= *n_tiles) return;
    int e = tile_e[ty], m0 = tile_m0[ty];
    int cnt = counts[e], moff = offs[e];
    int n0 = blockIdx.y * 128;
    const unsigned short* Bg = keysb + (size_t)e * Hc * Dc + (size_t)n0 * Dc;

    __shared__ unsigned short As[128 * BK];
    __shared__ unsigned short Bs[128 * BK];

    int t = threadIdx.x;
    int lane = t & 63, w = t >> 6;
    int Mq = (w & 1) * 64, Nq = (w >> 1) * 64;
    int l15 = lane & 15, l4 = lane >> 4;
    int rx = l15 & 7;

    floatx4 acc[4][4];
#pragma unroll
    for (int i = 0; i < 4; i++)
#pragma unroll
        for (int j = 0; j < 4; j++) acc[i][j] = (floatx4){0.f, 0.f, 0.f, 0.f};

    for (int kk = 0; kk < Dc; kk += BK) {
        __syncthreads();
        stage32(Xg, Dc, moff + m0 + w * 32, Pc + PADROWS - 1, kk, (char*)As + (size_t)w * 32 * 128, lane);
        stage32(Bg, Dc, w * 32, Hc - 1, kk, (char*)Bs + (size_t)w * 32 * 128, lane);
        __syncthreads();
#pragma unroll
        for (int s = 0; s < 2; s++) {
            bf16x8 af[4], bfr[4];
#pragma unroll
            for (int mi = 0; mi < 4; mi++)
                af[mi] = *(const bf16x8*)(As + (Mq + mi * 16 + l15) * BK + (((s * 4 + l4) ^ rx) * 8));
#pragma unroll
            for (int ni = 0; ni < 4; ni++)
                bfr[ni] = *(const bf16x8*)(Bs + (Nq + ni * 16 + l15) * BK + (((s * 4 + l4) ^ rx) * 8));
#pragma unroll
            for (int mi = 0; mi < 4; mi++)
#pragma unroll
                for (int ni = 0; ni < 4; ni++)
                    acc[mi][ni] = __builtin_amdgcn_mfma_f32_16x16x32_bf16(af[mi], bfr[ni], acc[mi][ni], 0, 0, 0);
        }
    }

#pragma unroll
    for (int mi = 0; mi < 4; mi++) {
#pragma unroll
        for (int r = 0; r < 4; r++) {
            int mloc = Mq + mi * 16 + l4 * 4 + r;
            int gm = m0 + mloc;
            if (gm < cnt) {
                size_t rowbase = (size_t)(moff + gm) * Hc + n0;
#pragma unroll
                for (int ni = 0; ni < 4; ni++) {
                    float g = gelu_fast(acc[mi][ni][r]);
                    hidden[rowbase + Nq + ni * 16 + l15] = f2bf(g);
                }
            }
        }
    }
}

// ================== GEMM2: out += w * (hidden . values^T) ==================
// 256x128 tile, 8 waves (512 threads), split-K=4, single-buffered.
// Wave grid 4x2 over 256x128 -> wave tile 64x64 (32 MFMA/wave/K-step preserved).
// LDS 48KB -> 2 blocks (16 waves)/CU. Grid: x = m256-tile (24%8==0 -> XCD A-sharing).
__global__ __launch_bounds__(512, 4) void gemm2_kernel(
    const unsigned short* __restrict__ hidden,  // [Pc+PADROWS, 2048] bf16
    const unsigned short* __restrict__ valsb,   // [E, 1024, 2048] bf16
    const int* __restrict__ counts, const int* __restrict__ offs,
    const int* __restrict__ t256_e, const int* __restrict__ t256_m0,
    const int* __restrict__ n_t256,
    const int* __restrict__ job_token, const float* __restrict__ job_w,
    float* __restrict__ out)
{
    int ty = blockIdx.x;
    if (ty >= *n_t256) return;
    int e = t256_e[ty], m0 = t256_m0[ty];
    int cnt = counts[e], moff = offs[e];
    int n0 = blockIdx.y * 128;
    int k_begin = blockIdx.z * (Hc / 4);
    int k_end = k_begin + (Hc / 4);
    const unsigned short* Bg = valsb + (size_t)e * Dc * Hc + (size_t)n0 * Hc;

    __shared__ unsigned short As[256 * BK];   // 32KB
    __shared__ unsigned short Bs[128 * BK];   // 16KB

    int t = threadIdx.x;
    int lane = t & 63, w = t >> 6;            // w = 0..7
    int Mq = (w & 3) * 64, Nq = (w >> 2) * 64;
    int l15 = lane & 15, l4 = lane >> 4;
    int rx = l15 & 7;

    floatx4 acc[4][4];
#pragma unroll
    for (int i = 0; i < 4; i++)
#pragma unroll
        for (int j = 0; j < 4; j++) acc[i][j] = (floatx4){0.f, 0.f, 0.f, 0.f};

    for (int kk = k_begin; kk < k_end; kk += BK) {
        __syncthreads();
        stage32(hidden, Hc, moff + m0 + w * 32, Pc + PADROWS - 1, kk, (char*)As + (size_t)w * 32 * 128, lane);
        stage16(Bg, Hc, w * 16, kk, (char*)Bs + (size_t)w * 16 * 128, lane);
        __syncthreads();
#pragma unroll
        for (int s = 0; s < 2; s++) {
            bf16x8 af[4], bfr[4];
#pragma unroll
            for (int mi = 0; mi < 4; mi++)
                af[mi] = *(const bf16x8*)(As + (Mq + mi * 16 + l15) * BK + (((s * 4 + l4) ^ rx) * 8));
#pragma unroll
            for (int ni = 0; ni < 4; ni++)
                bfr[ni] = *(const bf16x8*)(Bs + (Nq + ni * 16 + l15) * BK + (((s * 4 + l4) ^ rx) * 8));
#pragma unroll
            for (int mi = 0; mi < 4; mi++)
#pragma unroll
                for (int ni = 0; ni < 4; ni++)
                    acc[mi][ni] = __builtin_amdgcn_mfma_f32_16x16x32_bf16(af[mi], bfr[ni], acc[mi][ni], 0, 0, 0);
        }
    }

#pragma unroll
    for (int mi = 0; mi < 4; mi++) {
#pragma unroll
        for (int r = 0; r < 4; r++) {
            int mloc = Mq + mi * 16 + l4 * 4 + r;      // 0..255
            int gm = m0 + mloc;
            if (gm < cnt) {
                int tok = job_token[moff + gm];
                float wgt = job_w[moff + gm];
                float* orow = out + (size_t)tok * Dc + n0;
#pragma unroll
                for (int ni = 0; ni < 4; ni++) {
                    atomicAdd(orow + Nq + ni * 16 + l15, wgt * acc[mi][ni][r]);
                }
            }
        }
    }
}

// ---------- workspace layout (bytes) ----------
// counts     @ 0     (32)
// offs       @ 32    (36)
// n_tiles    @ 68    (4)
// n_t256     @ 72    (4)
// tile_e     @ 128   (160)
// tile_m0    @ 288   (160)
// t256_e     @ 448   (96)
// t256_m0    @ 544   (96)  -> header ends 640
// job_token  @ 640   (16384)
// job_w      @ 17024 (16384)
// Xg         @ 33408    ((4096+128)*1024*2 = 8650752)
// keysb      @ 8684160  (33554432)
// valsb      @ 42238592 (33554432)
// hidden     @ 75793024 ((4096+128)*2048*2 = 17301504) -> total 93094528 B

extern "C" void kernel_launch(void* const* d_in, const int* in_sizes, int n_in,
                              void* d_out, int out_size, void* d_ws, size_t ws_size,
                              hipStream_t stream) {
    const float* x      = (const float*)d_in[0];
    const float* keys   = (const float*)d_in[1];
    const float* values = (const float*)d_in[2];
    const int*   eidx   = (const int*)d_in[3];
    const float* ew     = (const float*)d_in[4];
    float* out = (float*)d_out;
    char* ws = (char*)d_ws;

    int*   counts    = (int*)(ws + 0);
    int*   offs      = (int*)(ws + 32);
    int*   n_tiles   = (int*)(ws + 68);
    int*   n_t256    = (int*)(ws + 72);
    int*   tile_e    = (int*)(ws + 128);
    int*   tile_m0   = (int*)(ws + 288);
    int*   t256_e    = (int*)(ws + 448);
    int*   t256_m0   = (int*)(ws + 544);
    int*   job_token = (int*)(ws + 640);
    float* job_w     = (float*)(ws + 17024);
    unsigned short* Xg     = (unsigned short*)(ws + 33408);
    unsigned short* keysb  = (unsigned short*)(ws + 8684160);
    unsigned short* valsb  = (unsigned short*)(ws + 42238592);
    unsigned short* hidden = (unsigned short*)(ws + 75793024);

    hipMemsetAsync(d_out, 0, (size_t)out_size * 4, stream);   // fp32 accum target

    bucket_kernel<<<1, 256, 0, stream>>>(eidx, ew, counts, offs, tile_e, tile_m0,
                                         t256_e, t256_m0, n_tiles, n_t256,
                                         job_token, job_w);

    const int n8each = (Ec * Hc * Dc) / 8;   // 2,097,152
    convert2_kernel<<<(2 * n8each) / 256, 256, 0, stream>>>(keys, keysb, values, valsb, n8each);
    gather_kernel<<<Pc, 256, 0, stream>>>(x, job_token, Xg);

    gemm1_kernel<<<dim3(MAXTILES, Hc / 128, 1), 256, 0, stream>>>(
        Xg, keysb, counts, offs, tile_e, tile_m0, n_tiles, hidden);
    gemm2_kernel<<<dim3(MAXT256, Dc / 128, 4), 512, 0, stream>>>(
        hidden, valsb, counts, offs, t256_e, t256_m0, n_t256, job_token, job_w, out);
}